// Round 15
// baseline (145.313 us; speedup 1.0000x reference)
//
#include <hip/hip_runtime.h>
#include <math.h>

#define B 2
#define L 512
#define DIN 400
#define D 256
#define H 8
#define DKK 32
#define DFF 1024
#define NL 2
#define NCLS 2

// ---------------------------------------------------------------------------
// K1: fused [reduce GEMM + SELU] (tasks 0..127) | prep (tasks 128..383)
// R9-verbatim.
// ---------------------------------------------------------------------------
__global__ __launch_bounds__(256) void k_init(
    const float* __restrict__ feature, const float* __restrict__ w_reduce,
    const float* __restrict__ b_reduce, float* __restrict__ x,
    const float* __restrict__ pos_w, const float* __restrict__ pos_b,
    float* __restrict__ T, float* __restrict__ pbm) {
  __shared__ float As[2][32][20];
  __shared__ float Bs[2][16][68];
  int tid = threadIdx.x;
  int task = blockIdx.x;
  if (task >= 128) {
    int t = task - 128;
    int c = t >> 7;
    float p = (float)((t & 127) - 64);
    int h = tid >> 5;
    int r2 = tid & 31;
    float val = 0.f;
#pragma unroll
    for (int rr = 0; rr < 2; ++rr) {
      int r = r2 + rr * 32;
      float inv = powf(10000.0f, -(float)r * (1.0f / 64.0f));
      float a = p * inv;
      const float* ps = pos_w + (size_t)(c * 128 + r) * D + h * DKK;
      const float* pc = pos_w + (size_t)(c * 128 + 64 + r) * D + h * DKK;
      float ss = 0.f, cs = 0.f;
#pragma unroll
      for (int d = 0; d < DKK; d += 4) {
        float4 v1 = *(const float4*)&ps[d];
        float4 v2 = *(const float4*)&pc[d];
        ss += v1.x + v1.y + v1.z + v1.w;
        cs += v2.x + v2.y + v2.z + v2.w;
      }
      val += sinf(a) * ss + cosf(a) * cs;
    }
    val *= (1.0f / DKK);
#pragma unroll
    for (int m2 = 16; m2; m2 >>= 1) val += __shfl_xor(val, m2);
    if (r2 == 0) T[t * 8 + h] = val;
    if (t == 0) {
      float pv = pos_b[h * DKK + r2];
#pragma unroll
      for (int m2 = 16; m2; m2 >>= 1) pv += __shfl_xor(pv, m2);
      if (r2 == 0) pbm[h] = pv * (1.0f / DKK);
    }
    return;
  }
  const int K = DIN, N = D;
  int m0 = (task >> 2) * 32;
  int n0 = (task & 3) * 64;
  int a_m = tid >> 3;
  int a_k = (tid & 7) * 2;
  int b_k = tid >> 4;
  int b_n = (tid & 15) * 4;
  const float* Aptr = feature + (size_t)(m0 + a_m) * K + a_k;
  const float* Wptr = w_reduce + (size_t)b_k * N + n0 + b_n;
  const int nT = K / 16;
  int tc = tid & 15;
  int tr = tid >> 4;
  float acc[2][4];
#pragma unroll
  for (int i = 0; i < 2; ++i)
#pragma unroll
    for (int j = 0; j < 4; ++j) acc[i][j] = 0.0f;
  float2 areg = *(const float2*)Aptr;
  float4 breg = *(const float4*)Wptr;
  int buf = 0;
  *(float2*)&As[0][a_m][a_k] = areg;
  *(float4*)&Bs[0][b_k][b_n] = breg;
  for (int t = 0; t < nT; ++t) {
    __syncthreads();
    if (t + 1 < nT) {
      areg = *(const float2*)(Aptr + (t + 1) * 16);
      breg = *(const float4*)(Wptr + (size_t)(t + 1) * 16 * N);
    }
#pragma unroll
    for (int k = 0; k < 16; ++k) {
      float a0 = As[buf][tr * 2 + 0][k];
      float a1 = As[buf][tr * 2 + 1][k];
      float4 b = *(const float4*)&Bs[buf][k][tc * 4];
      acc[0][0] += a0 * b.x; acc[0][1] += a0 * b.y;
      acc[0][2] += a0 * b.z; acc[0][3] += a0 * b.w;
      acc[1][0] += a1 * b.x; acc[1][1] += a1 * b.y;
      acc[1][2] += a1 * b.z; acc[1][3] += a1 * b.w;
    }
    __syncthreads();
    if (t + 1 < nT) {
      *(float2*)&As[buf ^ 1][a_m][a_k] = areg;
      *(float4*)&Bs[buf ^ 1][b_k][b_n] = breg;
    }
    buf ^= 1;
  }
  const float s_alpha = 1.6732632423543772f, s_scale = 1.0507009873554805f;
#pragma unroll
  for (int i = 0; i < 2; ++i) {
    int row = m0 + tr * 2 + i;
    float4 outv;
    float v;
    v = acc[i][0] + b_reduce[n0 + tc * 4 + 0];
    outv.x = s_scale * (v > 0.f ? v : s_alpha * expm1f(v));
    v = acc[i][1] + b_reduce[n0 + tc * 4 + 1];
    outv.y = s_scale * (v > 0.f ? v : s_alpha * expm1f(v));
    v = acc[i][2] + b_reduce[n0 + tc * 4 + 2];
    outv.z = s_scale * (v > 0.f ? v : s_alpha * expm1f(v));
    v = acc[i][3] + b_reduce[n0 + tc * 4 + 3];
    outv.w = s_scale * (v > 0.f ? v : s_alpha * expm1f(v));
    *(float4*)&x[(size_t)row * N + n0 + tc * 4] = outv;
  }
}

// ---------------------------------------------------------------------------
// GEMM, BM=32/BN=64/BK=16/TM=2/TN=4 — 3-buffer LDS pipeline, ONE barrier
// per K-tile (write t+1 and compute t never alias; compute t-1 on (t-1)%3).
// MODE 1: z selects. MODE 3: split-K 4. ACT: 1 relu (MODE==0 only)
// ---------------------------------------------------------------------------
template <int ACT, int MODE>
__global__ __launch_bounds__(256) void gemm_kernel(
    const float* __restrict__ A, const float* __restrict__ Wa,
    const float* __restrict__ Wb, const float* __restrict__ Wc,
    const float* __restrict__ bias, float* __restrict__ Ca,
    float* __restrict__ Cb, float* __restrict__ Cc, float* __restrict__ Cd,
    int M, int N, int K, int kMid) {
  __shared__ float As[3][32][20];
  __shared__ float Bs[3][16][68];
  int tid = threadIdx.x;
  int m0 = blockIdx.x * 32;
  int n0 = blockIdx.y * 64;
  const float* W = Wa;
  float* C = Ca;
  int kBeg = 0, kEnd = K;
  bool useBias = (bias != nullptr);
  if (MODE == 1) {
    W = blockIdx.z == 0 ? Wa : (blockIdx.z == 1 ? Wb : Wc);
    C = blockIdx.z == 0 ? Ca : (blockIdx.z == 1 ? Cb : Cc);
  } else if (MODE == 2) {
    kBeg = blockIdx.z == 0 ? 0 : kMid;
    kEnd = blockIdx.z == 0 ? kMid : K;
    C = blockIdx.z == 0 ? Ca : Cb;
    if (blockIdx.z != 0) useBias = false;
  } else if (MODE == 3) {
    int q = K / 4;
    kBeg = blockIdx.z * q;
    kEnd = kBeg + q;
    C = blockIdx.z == 0 ? Ca
        : (blockIdx.z == 1 ? Cb : (blockIdx.z == 2 ? Cc : Cd));
    if (blockIdx.z != 0) useBias = false;
  }
  int a_m = tid >> 3;
  int a_k = (tid & 7) * 2;
  int b_k = tid >> 4;
  int b_n = (tid & 15) * 4;
  const float* Aptr = A + (size_t)(m0 + a_m) * K + kBeg + a_k;
  const float* Wptr = W + (size_t)(kBeg + b_k) * N + n0 + b_n;
  int nT = (kEnd - kBeg) / 16;
  int tc = tid & 15;
  int tr = tid >> 4;
  float acc[2][4];
#pragma unroll
  for (int i = 0; i < 2; ++i)
#pragma unroll
    for (int j = 0; j < 4; ++j) acc[i][j] = 0.0f;

  // preload tile 0 to LDS[0]; tile 1 into regs
  float2 areg = *(const float2*)Aptr;
  float4 breg = *(const float4*)Wptr;
  *(float2*)&As[0][a_m][a_k] = areg;
  *(float4*)&Bs[0][b_k][b_n] = breg;
  if (nT > 1) {
    areg = *(const float2*)(Aptr + 16);
    breg = *(const float4*)(Wptr + (size_t)16 * N);
  }
  __syncthreads();

  for (int t = 0; t < nT; ++t) {
    int cbuf = t % 3;
    if (t + 1 < nT) {
      int wb = (t + 1) % 3;
      *(float2*)&As[wb][a_m][a_k] = areg;
      *(float4*)&Bs[wb][b_k][b_n] = breg;
    }
    if (t + 2 < nT) {
      areg = *(const float2*)(Aptr + (t + 2) * 16);
      breg = *(const float4*)(Wptr + (size_t)(t + 2) * 16 * N);
    }
    __syncthreads();
#pragma unroll
    for (int k = 0; k < 16; ++k) {
      float a0 = As[cbuf][tr * 2 + 0][k];
      float a1 = As[cbuf][tr * 2 + 1][k];
      float4 b = *(const float4*)&Bs[cbuf][k][tc * 4];
      acc[0][0] += a0 * b.x; acc[0][1] += a0 * b.y;
      acc[0][2] += a0 * b.z; acc[0][3] += a0 * b.w;
      acc[1][0] += a1 * b.x; acc[1][1] += a1 * b.y;
      acc[1][2] += a1 * b.z; acc[1][3] += a1 * b.w;
    }
  }
  float bb[4];
#pragma unroll
  for (int j = 0; j < 4; ++j) bb[j] = useBias ? bias[n0 + tc * 4 + j] : 0.0f;
#pragma unroll
  for (int i = 0; i < 2; ++i) {
    int row = m0 + tr * 2 + i;
    float4 outv;
    float v0 = acc[i][0] + bb[0], v1 = acc[i][1] + bb[1];
    float v2 = acc[i][2] + bb[2], v3 = acc[i][3] + bb[3];
    if (MODE == 0 && ACT == 1) {
      v0 = fmaxf(v0, 0.f); v1 = fmaxf(v1, 0.f);
      v2 = fmaxf(v2, 0.f); v3 = fmaxf(v3, 0.f);
    }
    outv.x = v0; outv.y = v1; outv.z = v2; outv.w = v3;
    *(float4*)&C[(size_t)row * N + n0 + tc * 4] = outv;
  }
}

// ---------------------------------------------------------------------------
// fused attn + wo + ln1 — R13-verbatim (direct L2 reads of T)
// ---------------------------------------------------------------------------
__global__ __launch_bounds__(256) void k_attn(
    const float* __restrict__ q, const float* __restrict__ kk,
    const float* __restrict__ vv, const float* __restrict__ pos_ind,
    const float* __restrict__ fmask, const float* __restrict__ Tg,
    const float* __restrict__ pbm, float* __restrict__ xio,
    const float* __restrict__ wo_l, const float* __restrict__ g1,
    const float* __restrict__ b1v) {
  __shared__ float qrow[256];
  __shared__ float orow[256];
  __shared__ float psh[8][64];
  __shared__ float red[8];
  __shared__ int jlist[64], p0s[64], p1s[64], wcnt[8], woff[8], njs;
  int tid = threadIdx.x;
  int lane = tid & 63;
  int wv = tid >> 6;
  int bi = blockIdx.x;
  int b = bi >> 9, i = bi & 511;
  qrow[tid] = q[(size_t)bi * D + tid];
  float fmi = fmask[bi];
  __syncthreads();
  bool mflag[2];
  unsigned long long ball[2];
#pragma unroll
  for (int u = 0; u < 2; ++u) {
    int j = u * 256 + tid;
    float fmj = fmask[b * L + j];
    bool aj = (1.0f - fmj) > 0.0f;
    bool ai = (1.0f - fmi) > 0.0f;
    int di = i - j;
    bool local_np = (di >= 9) || (di <= -8);
    int ad = di < 0 ? -di : di;
    bool dil_np = (ad & 15) != 0;
    bool m = (dil_np || aj || ai) && (local_np || aj);
    mflag[u] = m;
    ball[u] = __ballot(!m);
    if (lane == 0) wcnt[u * 4 + wv] = __popcll(ball[u]);
  }
  __syncthreads();
  if (tid == 0) {
    int s = 0;
    for (int w = 0; w < 8; ++w) { woff[w] = s; s += wcnt[w]; }
    njs = s;
  }
  __syncthreads();
#pragma unroll
  for (int u = 0; u < 2; ++u) {
    if (!mflag[u]) {
      int j = u * 256 + tid;
      int slot = woff[u * 4 + wv] + __popcll(ball[u] & ((1ull << lane) - 1ull));
      jlist[slot] = j;
      size_t pidx = ((size_t)bi * L + j) * 2;
      int p0 = (int)floorf(pos_ind[pidx]);
      int p1 = (int)floorf(pos_ind[pidx + 1]);
      p0s[slot] = min(max(p0, -64), 63) + 64;
      p1s[slot] = min(max(p1, -64), 63) + 192;
    }
  }
  __syncthreads();
  int nj = njs;
  const float scale = 0.17677669529663687f;
#pragma unroll
  for (int hu = 0; hu < 2; ++hu) {
    int h = wv + hu * 4;
    float sc = -1e30f;
    if (lane < nj) {
      int j = jlist[lane];
      const float4* kr4 = (const float4*)&kk[(size_t)(b * L + j) * D + h * DKK];
      const float4* qh4 = (const float4*)&qrow[h * DKK];
      float dot = 0.f;
#pragma unroll
      for (int dq = 0; dq < 8; ++dq) {
        float4 av = qh4[dq], bv = kr4[dq];
        dot += av.x * bv.x + av.y * bv.y + av.z * bv.z + av.w * bv.w;
      }
      sc = dot * scale + Tg[p0s[lane] * 8 + h] + Tg[p1s[lane] * 8 + h] + pbm[h];
    }
    float mx = sc;
#pragma unroll
    for (int m2 = 32; m2; m2 >>= 1) mx = fmaxf(mx, __shfl_xor(mx, m2));
    float e = (lane < nj) ? expf(sc - mx) : 0.0f;
    float ssum = e;
#pragma unroll
    for (int m2 = 32; m2; m2 >>= 1) ssum += __shfl_xor(ssum, m2);
    psh[h][lane] = e / ssum;
  }
  __syncthreads();
  int h2 = tid >> 5, d = tid & 31;
  float pv0 = 0.f, pv1 = 0.f;
  if (nj > 0) {
    int s2 = 0;
    for (; s2 + 1 < nj; s2 += 2) {
      pv0 += psh[h2][s2] * vv[(size_t)(b * L + jlist[s2]) * D + h2 * DKK + d];
      pv1 += psh[h2][s2 + 1] *
             vv[(size_t)(b * L + jlist[s2 + 1]) * D + h2 * DKK + d];
    }
    if (s2 < nj)
      pv0 += psh[h2][s2] * vv[(size_t)(b * L + jlist[s2]) * D + h2 * DKK + d];
  } else {
    for (int j = 0; j < L; ++j) pv0 += vv[(size_t)(b * L + j) * D + tid];
    pv0 *= (1.0f / L);
  }
  orow[tid] = pv0 + pv1;
  __syncthreads();
  float a0 = 0.f, a1 = 0.f, a2 = 0.f, a3 = 0.f;
  const float* wc = wo_l + tid;
  for (int kx = 0; kx < D; kx += 4) {
    a0 += orow[kx + 0] * wc[(size_t)(kx + 0) * D];
    a1 += orow[kx + 1] * wc[(size_t)(kx + 1) * D];
    a2 += orow[kx + 2] * wc[(size_t)(kx + 2) * D];
    a3 += orow[kx + 3] * wc[(size_t)(kx + 3) * D];
  }
  float o2 = (a0 + a1) + (a2 + a3);
  float val = xio[(size_t)bi * D + tid] + o2;
  float sum = val;
#pragma unroll
  for (int m2 = 32; m2; m2 >>= 1) sum += __shfl_xor(sum, m2);
  if (lane == 0) red[wv] = sum;
  __syncthreads();
  float mean = (red[0] + red[1] + red[2] + red[3]) * (1.0f / D);
  float dd = val - mean;
  float sq = dd * dd;
#pragma unroll
  for (int m2 = 32; m2; m2 >>= 1) sq += __shfl_xor(sq, m2);
  if (lane == 0) red[4 + wv] = sq;
  __syncthreads();
  float var = (red[4] + red[5] + red[6] + red[7]) * (1.0f / D);
  float rs = rsqrtf(var + 1e-5f);
  xio[(size_t)bi * D + tid] = dd * rs * g1[tid] + b1v[tid];
}

// ---------------------------------------------------------------------------
// ln2(l) fused with qkv(l+1) — R9-verbatim. grid (32,4,3).
// ---------------------------------------------------------------------------
__global__ __launch_bounds__(256) void k_ln2qkv(
    const float* __restrict__ xold, const float* __restrict__ t1,
    const float* __restrict__ t2, const float* __restrict__ t3,
    const float* __restrict__ t4, const float* __restrict__ g,
    const float* __restrict__ bta, const float* __restrict__ wq_l,
    const float* __restrict__ wk_l, const float* __restrict__ wv_l,
    float* __restrict__ q, float* __restrict__ kbuf, float* __restrict__ vbuf,
    float* __restrict__ xnew) {
  __shared__ float xs[32][260];
  __shared__ float Bs[2][16][68];
  int tid = threadIdx.x;
  int lane = tid & 63, wv = tid >> 6;
  int m0 = blockIdx.x * 32;
  for (int r8 = 0; r8 < 8; ++r8) {
    int lr = wv * 8 + r8;
    int base = (m0 + lr) * D + lane * 4;
    float4 r = *(const float4*)&xold[base];
    float4 y0 = *(const float4*)&t1[base];
    float4 y1 = *(const float4*)&t2[base];
    float4 y2 = *(const float4*)&t3[base];
    float4 y3 = *(const float4*)&t4[base];
    float val[4] = {r.x + y0.x + y1.x + y2.x + y3.x,
                    r.y + y0.y + y1.y + y2.y + y3.y,
                    r.z + y0.z + y1.z + y2.z + y3.z,
                    r.w + y0.w + y1.w + y2.w + y3.w};
    float s = val[0] + val[1] + val[2] + val[3];
#pragma unroll
    for (int m = 32; m; m >>= 1) s += __shfl_xor(s, m);
    float mean = s * (1.0f / D);
    float vvv = 0.f;
#pragma unroll
    for (int e = 0; e < 4; ++e) {
      float dd = val[e] - mean;
      vvv += dd * dd;
    }
#pragma unroll
    for (int m = 32; m; m >>= 1) vvv += __shfl_xor(vvv, m);
    float rs = rsqrtf(vvv * (1.0f / D) + 1e-5f);
    float4 gv = *(const float4*)&g[lane * 4];
    float4 bv = *(const float4*)&bta[lane * 4];
    float4 ov;
    ov.x = (val[0] - mean) * rs * gv.x + bv.x;
    ov.y = (val[1] - mean) * rs * gv.y + bv.y;
    ov.z = (val[2] - mean) * rs * gv.z + bv.z;
    ov.w = (val[3] - mean) * rs * gv.w + bv.w;
    *(float4*)&xs[lr][lane * 4] = ov;
  }
  __syncthreads();
  int z = blockIdx.z;
  const float* W = z == 0 ? wq_l : (z == 1 ? wk_l : wv_l);
  float* C = z == 0 ? q : (z == 1 ? kbuf : vbuf);
  int n0 = blockIdx.y * 64;
  int b_k = tid >> 4, b_n = (tid & 15) * 4;
  const float* Wptr = W + (size_t)b_k * D + n0 + b_n;
  int tc = tid & 15, tr = tid >> 4;
  float acc[2][4] = {{0, 0, 0, 0}, {0, 0, 0, 0}};
  float4 breg = *(const float4*)Wptr;
  int buf = 0;
  *(float4*)&Bs[0][b_k][b_n] = breg;
  for (int t = 0; t < 16; ++t) {
    __syncthreads();
    if (t + 1 < 16) breg = *(const float4*)(Wptr + (size_t)(t + 1) * 16 * D);
#pragma unroll
    for (int k = 0; k < 16; ++k) {
      float a0 = xs[tr * 2 + 0][t * 16 + k];
      float a1 = xs[tr * 2 + 1][t * 16 + k];
      float4 bvv = *(const float4*)&Bs[buf][k][tc * 4];
      acc[0][0] += a0 * bvv.x; acc[0][1] += a0 * bvv.y;
      acc[0][2] += a0 * bvv.z; acc[0][3] += a0 * bvv.w;
      acc[1][0] += a1 * bvv.x; acc[1][1] += a1 * bvv.y;
      acc[1][2] += a1 * bvv.z; acc[1][3] += a1 * bvv.w;
    }
    __syncthreads();
    if (t + 1 < 16) *(float4*)&Bs[buf ^ 1][b_k][b_n] = breg;
    buf ^= 1;
  }
#pragma unroll
  for (int i = 0; i < 2; ++i) {
    float4 o4 = {acc[i][0], acc[i][1], acc[i][2], acc[i][3]};
    *(float4*)&C[(size_t)(m0 + tr * 2 + i) * D + n0 + tc * 4] = o4;
  }
  if (blockIdx.y == 0 && z == 0) {
    for (int e = tid; e < 2048; e += 256) {
      int lr = e >> 6, c4 = e & 63;
      *(float4*)&xnew[(size_t)(m0 + lr) * D + c4 * 4] =
          *(const float4*)&xs[lr][c4 * 4];
    }
  }
}

// ---------------------------------------------------------------------------
// final: LN2 + classifier + 2-way softmax — R9-verbatim
// ---------------------------------------------------------------------------
__global__ __launch_bounds__(256) void ln_cls_kernel(
    const float* __restrict__ resid, const float* __restrict__ y0,
    const float* __restrict__ y1, const float* __restrict__ y2,
    const float* __restrict__ y3, const float* __restrict__ g,
    const float* __restrict__ bta, const float* __restrict__ cw,
    const float* __restrict__ cb, float* __restrict__ out) {
  int t = threadIdx.x;
  int lane = t & 63;
  int row = blockIdx.x * 4 + (t >> 6);
  int base = row * D + lane * 4;
  float4 r = *(const float4*)&resid[base];
  float4 a = *(const float4*)&y0[base];
  float4 c = *(const float4*)&y1[base];
  float4 d2 = *(const float4*)&y2[base];
  float4 e2 = *(const float4*)&y3[base];
  float val[4] = {r.x + a.x + c.x + d2.x + e2.x,
                  r.y + a.y + c.y + d2.y + e2.y,
                  r.z + a.z + c.z + d2.z + e2.z,
                  r.w + a.w + c.w + d2.w + e2.w};
  float s = val[0] + val[1] + val[2] + val[3];
#pragma unroll
  for (int m = 32; m; m >>= 1) s += __shfl_xor(s, m);
  float mean = s * (1.0f / D);
  float vv = 0.f;
#pragma unroll
  for (int e = 0; e < 4; ++e) {
    float dd = val[e] - mean;
    vv += dd * dd;
  }
#pragma unroll
  for (int m = 32; m; m >>= 1) vv += __shfl_xor(vv, m);
  float rs = rsqrtf(vv * (1.0f / D) + 1e-5f);
  float4 gv = *(const float4*)&g[lane * 4];
  float4 bv = *(const float4*)&bta[lane * 4];
  float xv[4];
  xv[0] = (val[0] - mean) * rs * gv.x + bv.x;
  xv[1] = (val[1] - mean) * rs * gv.y + bv.y;
  xv[2] = (val[2] - mean) * rs * gv.z + bv.z;
  xv[3] = (val[3] - mean) * rs * gv.w + bv.w;
  float l0 = 0.f, l1 = 0.f;
#pragma unroll
  for (int e = 0; e < 4; ++e) {
    int col = lane * 4 + e;
    l0 += xv[e] * cw[col * NCLS + 0];
    l1 += xv[e] * cw[col * NCLS + 1];
  }
#pragma unroll
  for (int m = 32; m; m >>= 1) {
    l0 += __shfl_xor(l0, m);
    l1 += __shfl_xor(l1, m);
  }
  if (lane == 0) {
    l0 += cb[0];
    l1 += cb[1];
    float mx = fmaxf(l0, l1);
    float e0 = expf(l0 - mx), e1 = expf(l1 - mx);
    float inv = 1.0f / (e0 + e1);
    out[row * 2 + 0] = e0 * inv;
    out[row * 2 + 1] = e1 * inv;
  }
}

extern "C" void kernel_launch(void* const* d_in, const int* in_sizes, int n_in,
                              void* d_out, int out_size, void* d_ws,
                              size_t ws_size, hipStream_t stream) {
  const float* feature  = (const float*)d_in[0];
  const float* pos_ind  = (const float*)d_in[1];
  const float* fmaskp   = (const float*)d_in[2];
  const float* w_reduce = (const float*)d_in[3];
  const float* b_reduce = (const float*)d_in[4];
  const float* pos_w    = (const float*)d_in[5];
  const float* pos_b    = (const float*)d_in[6];
  const float* wq       = (const float*)d_in[7];
  const float* wk       = (const float*)d_in[8];
  const float* wv       = (const float*)d_in[9];
  const float* wo       = (const float*)d_in[10];
  const float* ln1_g    = (const float*)d_in[11];
  const float* ln1_b    = (const float*)d_in[12];
  const float* w1       = (const float*)d_in[13];
  const float* b1       = (const float*)d_in[14];
  const float* w2       = (const float*)d_in[15];
  const float* b2       = (const float*)d_in[16];
  const float* ln2_g    = (const float*)d_in[17];
  const float* ln2_b    = (const float*)d_in[18];
  const float* cls_w    = (const float*)d_in[19];
  const float* cls_b    = (const float*)d_in[20];
  float* out = (float*)d_out;

  float* ws = (float*)d_ws;
  float* x0    = ws;  ws += B * L * D;
  float* x1    = ws;  ws += B * L * D;
  float* q     = ws;  ws += B * L * D;
  float* kbuf  = ws;  ws += B * L * D;
  float* vbuf  = ws;  ws += B * L * D;
  float* tmp1  = ws;  ws += B * L * D;
  float* tmp2  = ws;  ws += B * L * D;
  float* tmp3  = ws;  ws += B * L * D;
  float* tmp4  = ws;  ws += B * L * D;
  float* ffn_h = ws;  ws += B * L * DFF;
  float* T     = ws;  ws += 2048;
  float* pbm   = ws;  ws += 8;

  const int M = B * L;  // 1024

  k_init<<<384, 256, 0, stream>>>(feature, w_reduce, b_reduce, x0, pos_w,
                                  pos_b, T, pbm);
  // layer 0
  gemm_kernel<0, 1><<<dim3(32, 4, 3), 256, 0, stream>>>(
      x0, wq, wk, wv, nullptr, q, kbuf, vbuf, nullptr, M, D, D, 0);
  k_attn<<<M, 256, 0, stream>>>(q, kbuf, vbuf, pos_ind, fmaskp, T, pbm, x0,
                                wo, ln1_g, ln1_b);
  gemm_kernel<1, 0><<<dim3(32, 16), 256, 0, stream>>>(
      x0, w1, nullptr, nullptr, b1, ffn_h, nullptr, nullptr, nullptr, M, DFF,
      D, 0);
  gemm_kernel<0, 3><<<dim3(32, 4, 4), 256, 0, stream>>>(
      ffn_h, w2, nullptr, nullptr, b2, tmp1, tmp2, tmp3, tmp4, M, D, DFF, 0);
  // ln2(l0) + qkv(l1)
  k_ln2qkv<<<dim3(32, 4, 3), 256, 0, stream>>>(
      x0, tmp1, tmp2, tmp3, tmp4, ln2_g, ln2_b, wq + D * D, wk + D * D,
      wv + D * D, q, kbuf, vbuf, x1);
  // layer 1
  k_attn<<<M, 256, 0, stream>>>(q, kbuf, vbuf, pos_ind, fmaskp, T, pbm, x1,
                                wo + D * D, ln1_g + D, ln1_b + D);
  gemm_kernel<1, 0><<<dim3(32, 16), 256, 0, stream>>>(
      x1, w1 + D * DFF, nullptr, nullptr, b1 + DFF, ffn_h, nullptr, nullptr,
      nullptr, M, DFF, D, 0);
  gemm_kernel<0, 3><<<dim3(32, 4, 4), 256, 0, stream>>>(
      ffn_h, w2 + DFF * D, nullptr, nullptr, b2 + D, tmp1, tmp2, tmp3, tmp4,
      M, D, DFF, 0);
  ln_cls_kernel<<<M / 4, 256, 0, stream>>>(x1, tmp1, tmp2, tmp3, tmp4,
                                           ln2_g + D, ln2_b + D, cls_w, cls_b,
                                           out);
}

// Round 16
// 141.653 us; speedup vs baseline: 1.0258x; 1.0258x over previous
//
#include <hip/hip_runtime.h>
#include <math.h>

#define B 2
#define L 512
#define DIN 400
#define D 256
#define H 8
#define DKK 32
#define DFF 1024
#define NL 2
#define NCLS 2

// ---------------------------------------------------------------------------
// K1: fused [reduce GEMM + SELU] (tasks 0..127) | prep (tasks 128..383)
// ---------------------------------------------------------------------------
__global__ __launch_bounds__(256) void k_init(
    const float* __restrict__ feature, const float* __restrict__ w_reduce,
    const float* __restrict__ b_reduce, float* __restrict__ x,
    const float* __restrict__ pos_w, const float* __restrict__ pos_b,
    float* __restrict__ T, float* __restrict__ pbm) {
  __shared__ float As[2][32][20];
  __shared__ float Bs[2][16][68];
  int tid = threadIdx.x;
  int task = blockIdx.x;
  if (task >= 128) {
    int t = task - 128;
    int c = t >> 7;
    float p = (float)((t & 127) - 64);
    int h = tid >> 5;
    int r2 = tid & 31;
    float val = 0.f;
#pragma unroll
    for (int rr = 0; rr < 2; ++rr) {
      int r = r2 + rr * 32;
      float inv = powf(10000.0f, -(float)r * (1.0f / 64.0f));
      float a = p * inv;
      const float* ps = pos_w + (size_t)(c * 128 + r) * D + h * DKK;
      const float* pc = pos_w + (size_t)(c * 128 + 64 + r) * D + h * DKK;
      float ss = 0.f, cs = 0.f;
#pragma unroll
      for (int d = 0; d < DKK; d += 4) {
        float4 v1 = *(const float4*)&ps[d];
        float4 v2 = *(const float4*)&pc[d];
        ss += v1.x + v1.y + v1.z + v1.w;
        cs += v2.x + v2.y + v2.z + v2.w;
      }
      val += sinf(a) * ss + cosf(a) * cs;
    }
    val *= (1.0f / DKK);
#pragma unroll
    for (int m2 = 16; m2; m2 >>= 1) val += __shfl_xor(val, m2);
    if (r2 == 0) T[t * 8 + h] = val;
    if (t == 0) {
      float pv = pos_b[h * DKK + r2];
#pragma unroll
      for (int m2 = 16; m2; m2 >>= 1) pv += __shfl_xor(pv, m2);
      if (r2 == 0) pbm[h] = pv * (1.0f / DKK);
    }
    return;
  }
  const int K = DIN, N = D;
  int m0 = (task >> 2) * 32;
  int n0 = (task & 3) * 64;
  int a_m = tid >> 3;
  int a_k = (tid & 7) * 2;
  int b_k = tid >> 4;
  int b_n = (tid & 15) * 4;
  const float* Aptr = feature + (size_t)(m0 + a_m) * K + a_k;
  const float* Wptr = w_reduce + (size_t)b_k * N + n0 + b_n;
  const int nT = K / 16;
  int tc = tid & 15;
  int tr = tid >> 4;
  float acc[2][4];
#pragma unroll
  for (int i = 0; i < 2; ++i)
#pragma unroll
    for (int j = 0; j < 4; ++j) acc[i][j] = 0.0f;
  float2 areg = *(const float2*)Aptr;
  float4 breg = *(const float4*)Wptr;
  int buf = 0;
  *(float2*)&As[0][a_m][a_k] = areg;
  *(float4*)&Bs[0][b_k][b_n] = breg;
  for (int t = 0; t < nT; ++t) {
    __syncthreads();
    if (t + 1 < nT) {
      areg = *(const float2*)(Aptr + (t + 1) * 16);
      breg = *(const float4*)(Wptr + (size_t)(t + 1) * 16 * N);
    }
#pragma unroll
    for (int k = 0; k < 16; ++k) {
      float a0 = As[buf][tr * 2 + 0][k];
      float a1 = As[buf][tr * 2 + 1][k];
      float4 b = *(const float4*)&Bs[buf][k][tc * 4];
      acc[0][0] += a0 * b.x; acc[0][1] += a0 * b.y;
      acc[0][2] += a0 * b.z; acc[0][3] += a0 * b.w;
      acc[1][0] += a1 * b.x; acc[1][1] += a1 * b.y;
      acc[1][2] += a1 * b.z; acc[1][3] += a1 * b.w;
    }
    __syncthreads();
    if (t + 1 < nT) {
      *(float2*)&As[buf ^ 1][a_m][a_k] = areg;
      *(float4*)&Bs[buf ^ 1][b_k][b_n] = breg;
    }
    buf ^= 1;
  }
  const float s_alpha = 1.6732632423543772f, s_scale = 1.0507009873554805f;
#pragma unroll
  for (int i = 0; i < 2; ++i) {
    int row = m0 + tr * 2 + i;
    float4 outv;
    float v;
    v = acc[i][0] + b_reduce[n0 + tc * 4 + 0];
    outv.x = s_scale * (v > 0.f ? v : s_alpha * expm1f(v));
    v = acc[i][1] + b_reduce[n0 + tc * 4 + 1];
    outv.y = s_scale * (v > 0.f ? v : s_alpha * expm1f(v));
    v = acc[i][2] + b_reduce[n0 + tc * 4 + 2];
    outv.z = s_scale * (v > 0.f ? v : s_alpha * expm1f(v));
    v = acc[i][3] + b_reduce[n0 + tc * 4 + 3];
    outv.w = s_scale * (v > 0.f ? v : s_alpha * expm1f(v));
    *(float4*)&x[(size_t)row * N + n0 + tc * 4] = outv;
  }
}

// ---------------------------------------------------------------------------
// R5/R9-verbatim GEMM, BM=32/BN=64/BK=16/TM=2/TN=4, dbuf.
// MODE 1: z selects. MODE 3: split-K 4. ACT: 1 relu (MODE==0 only)
// ---------------------------------------------------------------------------
template <int ACT, int MODE>
__global__ __launch_bounds__(256) void gemm_kernel(
    const float* __restrict__ A, const float* __restrict__ Wa,
    const float* __restrict__ Wb, const float* __restrict__ Wc,
    const float* __restrict__ bias, float* __restrict__ Ca,
    float* __restrict__ Cb, float* __restrict__ Cc, float* __restrict__ Cd,
    int M, int N, int K, int kMid) {
  __shared__ float As[2][32][20];
  __shared__ float Bs[2][16][68];
  int tid = threadIdx.x;
  int m0 = blockIdx.x * 32;
  int n0 = blockIdx.y * 64;
  const float* W = Wa;
  float* C = Ca;
  int kBeg = 0, kEnd = K;
  bool useBias = (bias != nullptr);
  if (MODE == 1) {
    W = blockIdx.z == 0 ? Wa : (blockIdx.z == 1 ? Wb : Wc);
    C = blockIdx.z == 0 ? Ca : (blockIdx.z == 1 ? Cb : Cc);
  } else if (MODE == 2) {
    kBeg = blockIdx.z == 0 ? 0 : kMid;
    kEnd = blockIdx.z == 0 ? kMid : K;
    C = blockIdx.z == 0 ? Ca : Cb;
    if (blockIdx.z != 0) useBias = false;
  } else if (MODE == 3) {
    int q = K / 4;
    kBeg = blockIdx.z * q;
    kEnd = kBeg + q;
    C = blockIdx.z == 0 ? Ca
        : (blockIdx.z == 1 ? Cb : (blockIdx.z == 2 ? Cc : Cd));
    if (blockIdx.z != 0) useBias = false;
  }
  int a_m = tid >> 3;
  int a_k = (tid & 7) * 2;
  int b_k = tid >> 4;
  int b_n = (tid & 15) * 4;
  const float* Aptr = A + (size_t)(m0 + a_m) * K + kBeg + a_k;
  const float* Wptr = W + (size_t)(kBeg + b_k) * N + n0 + b_n;
  int nT = (kEnd - kBeg) / 16;
  int tc = tid & 15;
  int tr = tid >> 4;
  float acc[2][4];
#pragma unroll
  for (int i = 0; i < 2; ++i)
#pragma unroll
    for (int j = 0; j < 4; ++j) acc[i][j] = 0.0f;

  float2 areg = *(const float2*)Aptr;
  float4 breg = *(const float4*)Wptr;
  int buf = 0;
  *(float2*)&As[0][a_m][a_k] = areg;
  *(float4*)&Bs[0][b_k][b_n] = breg;

  for (int t = 0; t < nT; ++t) {
    __syncthreads();
    if (t + 1 < nT) {
      areg = *(const float2*)(Aptr + (t + 1) * 16);
      breg = *(const float4*)(Wptr + (size_t)(t + 1) * 16 * N);
    }
#pragma unroll
    for (int k = 0; k < 16; ++k) {
      float a0 = As[buf][tr * 2 + 0][k];
      float a1 = As[buf][tr * 2 + 1][k];
      float4 b = *(const float4*)&Bs[buf][k][tc * 4];
      acc[0][0] += a0 * b.x; acc[0][1] += a0 * b.y;
      acc[0][2] += a0 * b.z; acc[0][3] += a0 * b.w;
      acc[1][0] += a1 * b.x; acc[1][1] += a1 * b.y;
      acc[1][2] += a1 * b.z; acc[1][3] += a1 * b.w;
    }
    __syncthreads();
    if (t + 1 < nT) {
      *(float2*)&As[buf ^ 1][a_m][a_k] = areg;
      *(float4*)&Bs[buf ^ 1][b_k][b_n] = breg;
    }
    buf ^= 1;
  }
  float bb[4];
#pragma unroll
  for (int j = 0; j < 4; ++j) bb[j] = useBias ? bias[n0 + tc * 4 + j] : 0.0f;
#pragma unroll
  for (int i = 0; i < 2; ++i) {
    int row = m0 + tr * 2 + i;
    float4 outv;
    float v0 = acc[i][0] + bb[0], v1 = acc[i][1] + bb[1];
    float v2 = acc[i][2] + bb[2], v3 = acc[i][3] + bb[3];
    if (MODE == 0 && ACT == 1) {
      v0 = fmaxf(v0, 0.f); v1 = fmaxf(v1, 0.f);
      v2 = fmaxf(v2, 0.f); v3 = fmaxf(v3, 0.f);
    }
    outv.x = v0; outv.y = v1; outv.z = v2; outv.w = v3;
    *(float4*)&C[(size_t)row * N + n0 + tc * 4] = outv;
  }
}

// ---------------------------------------------------------------------------
// fused attn + wo + ln1 — direct L2 reads of T (R13-verbatim)
// ---------------------------------------------------------------------------
__global__ __launch_bounds__(256) void k_attn(
    const float* __restrict__ q, const float* __restrict__ kk,
    const float* __restrict__ vv, const float* __restrict__ pos_ind,
    const float* __restrict__ fmask, const float* __restrict__ Tg,
    const float* __restrict__ pbm, float* __restrict__ xio,
    const float* __restrict__ wo_l, const float* __restrict__ g1,
    const float* __restrict__ b1v) {
  __shared__ float qrow[256];
  __shared__ float orow[256];
  __shared__ float psh[8][64];
  __shared__ float red[8];
  __shared__ int jlist[64], p0s[64], p1s[64], wcnt[8], woff[8], njs;
  int tid = threadIdx.x;
  int lane = tid & 63;
  int wv = tid >> 6;
  int bi = blockIdx.x;
  int b = bi >> 9, i = bi & 511;
  qrow[tid] = q[(size_t)bi * D + tid];
  float fmi = fmask[bi];
  __syncthreads();
  bool mflag[2];
  unsigned long long ball[2];
#pragma unroll
  for (int u = 0; u < 2; ++u) {
    int j = u * 256 + tid;
    float fmj = fmask[b * L + j];
    bool aj = (1.0f - fmj) > 0.0f;
    bool ai = (1.0f - fmi) > 0.0f;
    int di = i - j;
    bool local_np = (di >= 9) || (di <= -8);
    int ad = di < 0 ? -di : di;
    bool dil_np = (ad & 15) != 0;
    bool m = (dil_np || aj || ai) && (local_np || aj);
    mflag[u] = m;
    ball[u] = __ballot(!m);
    if (lane == 0) wcnt[u * 4 + wv] = __popcll(ball[u]);
  }
  __syncthreads();
  if (tid == 0) {
    int s = 0;
    for (int w = 0; w < 8; ++w) { woff[w] = s; s += wcnt[w]; }
    njs = s;
  }
  __syncthreads();
#pragma unroll
  for (int u = 0; u < 2; ++u) {
    if (!mflag[u]) {
      int j = u * 256 + tid;
      int slot = woff[u * 4 + wv] + __popcll(ball[u] & ((1ull << lane) - 1ull));
      jlist[slot] = j;
      size_t pidx = ((size_t)bi * L + j) * 2;
      int p0 = (int)floorf(pos_ind[pidx]);
      int p1 = (int)floorf(pos_ind[pidx + 1]);
      p0s[slot] = min(max(p0, -64), 63) + 64;
      p1s[slot] = min(max(p1, -64), 63) + 192;
    }
  }
  __syncthreads();
  int nj = njs;
  const float scale = 0.17677669529663687f;
#pragma unroll
  for (int hu = 0; hu < 2; ++hu) {
    int h = wv + hu * 4;
    float sc = -1e30f;
    if (lane < nj) {
      int j = jlist[lane];
      const float4* kr4 = (const float4*)&kk[(size_t)(b * L + j) * D + h * DKK];
      const float4* qh4 = (const float4*)&qrow[h * DKK];
      float dot = 0.f;
#pragma unroll
      for (int dq = 0; dq < 8; ++dq) {
        float4 av = qh4[dq], bv = kr4[dq];
        dot += av.x * bv.x + av.y * bv.y + av.z * bv.z + av.w * bv.w;
      }
      sc = dot * scale + Tg[p0s[lane] * 8 + h] + Tg[p1s[lane] * 8 + h] + pbm[h];
    }
    float mx = sc;
#pragma unroll
    for (int m2 = 32; m2; m2 >>= 1) mx = fmaxf(mx, __shfl_xor(mx, m2));
    float e = (lane < nj) ? expf(sc - mx) : 0.0f;
    float ssum = e;
#pragma unroll
    for (int m2 = 32; m2; m2 >>= 1) ssum += __shfl_xor(ssum, m2);
    psh[h][lane] = e / ssum;
  }
  __syncthreads();
  int h2 = tid >> 5, d = tid & 31;
  float pv0 = 0.f, pv1 = 0.f;
  if (nj > 0) {
    int s2 = 0;
    for (; s2 + 1 < nj; s2 += 2) {
      pv0 += psh[h2][s2] * vv[(size_t)(b * L + jlist[s2]) * D + h2 * DKK + d];
      pv1 += psh[h2][s2 + 1] *
             vv[(size_t)(b * L + jlist[s2 + 1]) * D + h2 * DKK + d];
    }
    if (s2 < nj)
      pv0 += psh[h2][s2] * vv[(size_t)(b * L + jlist[s2]) * D + h2 * DKK + d];
  } else {
    for (int j = 0; j < L; ++j) pv0 += vv[(size_t)(b * L + j) * D + tid];
    pv0 *= (1.0f / L);
  }
  orow[tid] = pv0 + pv1;
  __syncthreads();
  float a0 = 0.f, a1 = 0.f, a2 = 0.f, a3 = 0.f;
  const float* wc = wo_l + tid;
  for (int kx = 0; kx < D; kx += 4) {
    a0 += orow[kx + 0] * wc[(size_t)(kx + 0) * D];
    a1 += orow[kx + 1] * wc[(size_t)(kx + 1) * D];
    a2 += orow[kx + 2] * wc[(size_t)(kx + 2) * D];
    a3 += orow[kx + 3] * wc[(size_t)(kx + 3) * D];
  }
  float o2 = (a0 + a1) + (a2 + a3);
  float val = xio[(size_t)bi * D + tid] + o2;
  float sum = val;
#pragma unroll
  for (int m2 = 32; m2; m2 >>= 1) sum += __shfl_xor(sum, m2);
  if (lane == 0) red[wv] = sum;
  __syncthreads();
  float mean = (red[0] + red[1] + red[2] + red[3]) * (1.0f / D);
  float dd = val - mean;
  float sq = dd * dd;
#pragma unroll
  for (int m2 = 32; m2; m2 >>= 1) sq += __shfl_xor(sq, m2);
  if (lane == 0) red[4 + wv] = sq;
  __syncthreads();
  float var = (red[4] + red[5] + red[6] + red[7]) * (1.0f / D);
  float rs = rsqrtf(var + 1e-5f);
  xio[(size_t)bi * D + tid] = dd * rs * g1[tid] + b1v[tid];
}

// ---------------------------------------------------------------------------
// ln2(l) fused with qkv(l+1) — R9-verbatim. grid (32,4,3).
// ---------------------------------------------------------------------------
__global__ __launch_bounds__(256) void k_ln2qkv(
    const float* __restrict__ xold, const float* __restrict__ t1,
    const float* __restrict__ t2, const float* __restrict__ t3,
    const float* __restrict__ t4, const float* __restrict__ g,
    const float* __restrict__ bta, const float* __restrict__ wq_l,
    const float* __restrict__ wk_l, const float* __restrict__ wv_l,
    float* __restrict__ q, float* __restrict__ kbuf, float* __restrict__ vbuf,
    float* __restrict__ xnew) {
  __shared__ float xs[32][260];
  __shared__ float Bs[2][16][68];
  int tid = threadIdx.x;
  int lane = tid & 63, wv = tid >> 6;
  int m0 = blockIdx.x * 32;
  for (int r8 = 0; r8 < 8; ++r8) {
    int lr = wv * 8 + r8;
    int base = (m0 + lr) * D + lane * 4;
    float4 r = *(const float4*)&xold[base];
    float4 y0 = *(const float4*)&t1[base];
    float4 y1 = *(const float4*)&t2[base];
    float4 y2 = *(const float4*)&t3[base];
    float4 y3 = *(const float4*)&t4[base];
    float val[4] = {r.x + y0.x + y1.x + y2.x + y3.x,
                    r.y + y0.y + y1.y + y2.y + y3.y,
                    r.z + y0.z + y1.z + y2.z + y3.z,
                    r.w + y0.w + y1.w + y2.w + y3.w};
    float s = val[0] + val[1] + val[2] + val[3];
#pragma unroll
    for (int m = 32; m; m >>= 1) s += __shfl_xor(s, m);
    float mean = s * (1.0f / D);
    float vvv = 0.f;
#pragma unroll
    for (int e = 0; e < 4; ++e) {
      float dd = val[e] - mean;
      vvv += dd * dd;
    }
#pragma unroll
    for (int m = 32; m; m >>= 1) vvv += __shfl_xor(vvv, m);
    float rs = rsqrtf(vvv * (1.0f / D) + 1e-5f);
    float4 gv = *(const float4*)&g[lane * 4];
    float4 bv = *(const float4*)&bta[lane * 4];
    float4 ov;
    ov.x = (val[0] - mean) * rs * gv.x + bv.x;
    ov.y = (val[1] - mean) * rs * gv.y + bv.y;
    ov.z = (val[2] - mean) * rs * gv.z + bv.z;
    ov.w = (val[3] - mean) * rs * gv.w + bv.w;
    *(float4*)&xs[lr][lane * 4] = ov;
  }
  __syncthreads();
  int z = blockIdx.z;
  const float* W = z == 0 ? wq_l : (z == 1 ? wk_l : wv_l);
  float* C = z == 0 ? q : (z == 1 ? kbuf : vbuf);
  int n0 = blockIdx.y * 64;
  int b_k = tid >> 4, b_n = (tid & 15) * 4;
  const float* Wptr = W + (size_t)b_k * D + n0 + b_n;
  int tc = tid & 15, tr = tid >> 4;
  float acc[2][4] = {{0, 0, 0, 0}, {0, 0, 0, 0}};
  float4 breg = *(const float4*)Wptr;
  int buf = 0;
  *(float4*)&Bs[0][b_k][b_n] = breg;
  for (int t = 0; t < 16; ++t) {
    __syncthreads();
    if (t + 1 < 16) breg = *(const float4*)(Wptr + (size_t)(t + 1) * 16 * D);
#pragma unroll
    for (int k = 0; k < 16; ++k) {
      float a0 = xs[tr * 2 + 0][t * 16 + k];
      float a1 = xs[tr * 2 + 1][t * 16 + k];
      float4 bvv = *(const float4*)&Bs[buf][k][tc * 4];
      acc[0][0] += a0 * bvv.x; acc[0][1] += a0 * bvv.y;
      acc[0][2] += a0 * bvv.z; acc[0][3] += a0 * bvv.w;
      acc[1][0] += a1 * bvv.x; acc[1][1] += a1 * bvv.y;
      acc[1][2] += a1 * bvv.z; acc[1][3] += a1 * bvv.w;
    }
    __syncthreads();
    if (t + 1 < 16) *(float4*)&Bs[buf ^ 1][b_k][b_n] = breg;
    buf ^= 1;
  }
#pragma unroll
  for (int i = 0; i < 2; ++i) {
    float4 o4 = {acc[i][0], acc[i][1], acc[i][2], acc[i][3]};
    *(float4*)&C[(size_t)(m0 + tr * 2 + i) * D + n0 + tc * 4] = o4;
  }
  if (blockIdx.y == 0 && z == 0) {
    for (int e = tid; e < 2048; e += 256) {
      int lr = e >> 6, c4 = e & 63;
      *(float4*)&xnew[(size_t)(m0 + lr) * D + c4 * 4] =
          *(const float4*)&xs[lr][c4 * 4];
    }
  }
}

// ---------------------------------------------------------------------------
// final: LN2 + classifier + 2-way softmax — R9-verbatim
// ---------------------------------------------------------------------------
__global__ __launch_bounds__(256) void ln_cls_kernel(
    const float* __restrict__ resid, const float* __restrict__ y0,
    const float* __restrict__ y1, const float* __restrict__ y2,
    const float* __restrict__ y3, const float* __restrict__ g,
    const float* __restrict__ bta, const float* __restrict__ cw,
    const float* __restrict__ cb, float* __restrict__ out) {
  int t = threadIdx.x;
  int lane = t & 63;
  int row = blockIdx.x * 4 + (t >> 6);
  int base = row * D + lane * 4;
  float4 r = *(const float4*)&resid[base];
  float4 a = *(const float4*)&y0[base];
  float4 c = *(const float4*)&y1[base];
  float4 d2 = *(const float4*)&y2[base];
  float4 e2 = *(const float4*)&y3[base];
  float val[4] = {r.x + a.x + c.x + d2.x + e2.x,
                  r.y + a.y + c.y + d2.y + e2.y,
                  r.z + a.z + c.z + d2.z + e2.z,
                  r.w + a.w + c.w + d2.w + e2.w};
  float s = val[0] + val[1] + val[2] + val[3];
#pragma unroll
  for (int m = 32; m; m >>= 1) s += __shfl_xor(s, m);
  float mean = s * (1.0f / D);
  float vv = 0.f;
#pragma unroll
  for (int e = 0; e < 4; ++e) {
    float dd = val[e] - mean;
    vv += dd * dd;
  }
#pragma unroll
  for (int m = 32; m; m >>= 1) vv += __shfl_xor(vv, m);
  float rs = rsqrtf(vv * (1.0f / D) + 1e-5f);
  float4 gv = *(const float4*)&g[lane * 4];
  float4 bv = *(const float4*)&bta[lane * 4];
  float xv[4];
  xv[0] = (val[0] - mean) * rs * gv.x + bv.x;
  xv[1] = (val[1] - mean) * rs * gv.y + bv.y;
  xv[2] = (val[2] - mean) * rs * gv.z + bv.z;
  xv[3] = (val[3] - mean) * rs * gv.w + bv.w;
  float l0 = 0.f, l1 = 0.f;
#pragma unroll
  for (int e = 0; e < 4; ++e) {
    int col = lane * 4 + e;
    l0 += xv[e] * cw[col * NCLS + 0];
    l1 += xv[e] * cw[col * NCLS + 1];
  }
#pragma unroll
  for (int m = 32; m; m >>= 1) {
    l0 += __shfl_xor(l0, m);
    l1 += __shfl_xor(l1, m);
  }
  if (lane == 0) {
    l0 += cb[0];
    l1 += cb[1];
    float mx = fmaxf(l0, l1);
    float e0 = expf(l0 - mx), e1 = expf(l1 - mx);
    float inv = 1.0f / (e0 + e1);
    out[row * 2 + 0] = e0 * inv;
    out[row * 2 + 1] = e1 * inv;
  }
}

extern "C" void kernel_launch(void* const* d_in, const int* in_sizes, int n_in,
                              void* d_out, int out_size, void* d_ws,
                              size_t ws_size, hipStream_t stream) {
  const float* feature  = (const float*)d_in[0];
  const float* pos_ind  = (const float*)d_in[1];
  const float* fmaskp   = (const float*)d_in[2];
  const float* w_reduce = (const float*)d_in[3];
  const float* b_reduce = (const float*)d_in[4];
  const float* pos_w    = (const float*)d_in[5];
  const float* pos_b    = (const float*)d_in[6];
  const float* wq       = (const float*)d_in[7];
  const float* wk       = (const float*)d_in[8];
  const float* wv       = (const float*)d_in[9];
  const float* wo       = (const float*)d_in[10];
  const float* ln1_g    = (const float*)d_in[11];
  const float* ln1_b    = (const float*)d_in[12];
  const float* w1       = (const float*)d_in[13];
  const float* b1       = (const float*)d_in[14];
  const float* w2       = (const float*)d_in[15];
  const float* b2       = (const float*)d_in[16];
  const float* ln2_g    = (const float*)d_in[17];
  const float* ln2_b    = (const float*)d_in[18];
  const float* cls_w    = (const float*)d_in[19];
  const float* cls_b    = (const float*)d_in[20];
  float* out = (float*)d_out;

  float* ws = (float*)d_ws;
  float* x0    = ws;  ws += B * L * D;
  float* x1    = ws;  ws += B * L * D;
  float* q     = ws;  ws += B * L * D;
  float* kbuf  = ws;  ws += B * L * D;
  float* vbuf  = ws;  ws += B * L * D;
  float* tmp1  = ws;  ws += B * L * D;
  float* tmp2  = ws;  ws += B * L * D;
  float* tmp3  = ws;  ws += B * L * D;
  float* tmp4  = ws;  ws += B * L * D;
  float* ffn_h = ws;  ws += B * L * DFF;
  float* T     = ws;  ws += 2048;
  float* pbm   = ws;  ws += 8;

  const int M = B * L;  // 1024

  k_init<<<384, 256, 0, stream>>>(feature, w_reduce, b_reduce, x0, pos_w,
                                  pos_b, T, pbm);
  // layer 0
  gemm_kernel<0, 1><<<dim3(32, 4, 3), 256, 0, stream>>>(
      x0, wq, wk, wv, nullptr, q, kbuf, vbuf, nullptr, M, D, D, 0);
  k_attn<<<M, 256, 0, stream>>>(q, kbuf, vbuf, pos_ind, fmaskp, T, pbm, x0,
                                wo, ln1_g, ln1_b);
  gemm_kernel<1, 0><<<dim3(32, 16), 256, 0, stream>>>(
      x0, w1, nullptr, nullptr, b1, ffn_h, nullptr, nullptr, nullptr, M, DFF,
      D, 0);
  gemm_kernel<0, 3><<<dim3(32, 4, 4), 256, 0, stream>>>(
      ffn_h, w2, nullptr, nullptr, b2, tmp1, tmp2, tmp3, tmp4, M, D, DFF, 0);
  // ln2(l0) + qkv(l1)
  k_ln2qkv<<<dim3(32, 4, 3), 256, 0, stream>>>(
      x0, tmp1, tmp2, tmp3, tmp4, ln2_g, ln2_b, wq + D * D, wk + D * D,
      wv + D * D, q, kbuf, vbuf, x1);
  // layer 1
  k_attn<<<M, 256, 0, stream>>>(q, kbuf, vbuf, pos_ind, fmaskp, T, pbm, x1,
                                wo + D * D, ln1_g + D, ln1_b + D);
  gemm_kernel<1, 0><<<dim3(32, 16), 256, 0, stream>>>(
      x1, w1 + D * DFF, nullptr, nullptr, b1 + DFF, ffn_h, nullptr, nullptr,
      nullptr, M, DFF, D, 0);
  gemm_kernel<0, 3><<<dim3(32, 4, 4), 256, 0, stream>>>(
      ffn_h, w2 + DFF * D, nullptr, nullptr, b2 + D, tmp1, tmp2, tmp3, tmp4,
      M, D, DFF, 0);
  ln_cls_kernel<<<M / 4, 256, 0, stream>>>(x1, tmp1, tmp2, tmp3, tmp4,
                                           ln2_g + D, ln2_b + D, cls_w, cls_b,
                                           out);
}